// Round 1
// baseline (2240.723 us; speedup 1.0000x reference)
//
#include <hip/hip_runtime.h>
#include <math.h>

// Problem constants (from reference setup_inputs)
constexpr int B   = 16;
constexpr int C   = 256;
constexpr int H   = 64;
constexpr int W   = 64;
constexpr int K   = 4;
constexpr int O   = 256;
constexpr int HID = 65;            // int(256*0.25)+1
constexpr float TEMP = 34.0f;

// Conv tiling
constexpr int TILE_H = 32;         // output rows per block
constexpr int TILE_W = 64;         // output cols per block (full width)
constexpr int CC     = 4;          // input channels per chunk
constexpr int OT     = 8;          // output channels per block (and per thread)
constexpr int PX     = 8;          // pixels (consecutive cols) per thread
constexpr int XS_STRIDE = TILE_W + 2 + 1;  // 67: halo 66 + 1 pad (bank spread)

// ---------------------------------------------------------------------------
// Kernel 1: global average pool  pooled[b,c] = mean(x[b,c,:,:])
// grid = B*C blocks, 256 threads
// ---------------------------------------------------------------------------
__global__ void pool_kernel(const float* __restrict__ x, float* __restrict__ pooled) {
    const int bc = blockIdx.x;
    const float4* p4 = (const float4*)(x + (size_t)bc * (H * W));
    const int tid = threadIdx.x;
    float s = 0.f;
    #pragma unroll
    for (int i = 0; i < (H * W / 4) / 256; ++i) {
        float4 v = p4[tid + i * 256];
        s += (v.x + v.y) + (v.z + v.w);
    }
    // wave64 reduce
    #pragma unroll
    for (int off = 32; off > 0; off >>= 1) s += __shfl_down(s, off, 64);
    __shared__ float red[4];
    if ((tid & 63) == 0) red[tid >> 6] = s;
    __syncthreads();
    if (tid == 0) {
        float t = (red[0] + red[1]) + (red[2] + red[3]);
        pooled[bc] = t * (1.0f / (H * W));
    }
}

// ---------------------------------------------------------------------------
// Kernel 2: attention  att[b,k] = softmax_k( (relu(pooled@W1^T)@W2^T + b2)/T )
// grid = B blocks, 128 threads. Tiny.
// ---------------------------------------------------------------------------
__global__ void attention_kernel(const float* __restrict__ pooled,
                                 const float* __restrict__ w_fc1,
                                 const float* __restrict__ w_fc2,
                                 const float* __restrict__ b_fc2,
                                 float* __restrict__ att) {
    const int b = blockIdx.x;
    const int tid = threadIdx.x;
    __shared__ float pool_s[C];
    __shared__ float h_s[HID];
    __shared__ float logit_s[K];

    for (int i = tid; i < C; i += blockDim.x) pool_s[i] = pooled[b * C + i];
    __syncthreads();

    for (int j = tid; j < HID; j += blockDim.x) {
        const float* wr = w_fc1 + (size_t)j * C;
        float s = 0.f;
        #pragma unroll 4
        for (int c = 0; c < C; ++c) s += pool_s[c] * wr[c];
        h_s[j] = fmaxf(s, 0.f);
    }
    __syncthreads();

    if (tid < K) {
        const float* wr = w_fc2 + (size_t)tid * HID;
        float s = b_fc2[tid];
        for (int j = 0; j < HID; ++j) s += h_s[j] * wr[j];
        logit_s[tid] = s * (1.0f / TEMP);
    }
    __syncthreads();

    if (tid == 0) {
        float m = fmaxf(fmaxf(logit_s[0], logit_s[1]), fmaxf(logit_s[2], logit_s[3]));
        float e0 = expf(logit_s[0] - m);
        float e1 = expf(logit_s[1] - m);
        float e2 = expf(logit_s[2] - m);
        float e3 = expf(logit_s[3] - m);
        float inv = 1.0f / (e0 + e1 + e2 + e3);
        att[b * K + 0] = e0 * inv;
        att[b * K + 1] = e1 * inv;
        att[b * K + 2] = e2 * inv;
        att[b * K + 3] = e3 * inv;
    }
}

// ---------------------------------------------------------------------------
// Kernel 3: dynamic conv. Fused attention-weighted kernel aggregation + 3x3
// conv (pad 1) + bias. Each block: 8 o's x 32x64 pixel tile for one sample.
// Each thread: 8 o x 8 consecutive pixels (64 fp32 accumulators).
// ---------------------------------------------------------------------------
__global__ __launch_bounds__(256, 2)
void conv_kernel(const float* __restrict__ x,
                 const float* __restrict__ weight,   // [K,O,C,3,3]
                 const float* __restrict__ bias,     // [K,O]
                 const float* __restrict__ att,      // [B,K]
                 float* __restrict__ out) {
    const int tile_y = blockIdx.x;          // 0..1
    const int o0     = blockIdx.y * OT;     // 0..248
    const int b      = blockIdx.z;          // 0..15

    const int tid = threadIdx.x;
    const int tx  = tid & 7;                // col group: cols [8*tx, 8*tx+8)
    const int ty  = tid >> 3;               // row 0..31

    const int ty0 = tile_y * TILE_H;

    __shared__ __align__(16) float xs[CC][TILE_H + 2][XS_STRIDE];
    __shared__ __align__(16) float ws_s[OT][CC][12];   // taps padded 9->12

    // attention weights for this sample
    const float a0 = att[b * K + 0];
    const float a1 = att[b * K + 1];
    const float a2 = att[b * K + 2];
    const float a3 = att[b * K + 3];

    float acc[OT][PX];
    #pragma unroll
    for (int o = 0; o < OT; ++o)
        #pragma unroll
        for (int p = 0; p < PX; ++p) acc[o][p] = 0.f;

    const float* xb = x + (size_t)b * C * H * W;

    constexpr int X_ELEMS = CC * (TILE_H + 2) * (TILE_W + 2);   // 4*34*66 = 8976
    constexpr int W_ELEMS = OT * CC * 9;                        // 288

    for (int c0 = 0; c0 < C; c0 += CC) {
        __syncthreads();   // protect previous chunk's LDS from overwrite

        // ---- stage x halo tile (zero-padded) ----
        for (int idx = tid; idx < X_ELEMS; idx += 256) {
            int cc  = idx / ((TILE_H + 2) * (TILE_W + 2));
            int rem = idx - cc * ((TILE_H + 2) * (TILE_W + 2));
            int r   = rem / (TILE_W + 2);
            int col = rem - r * (TILE_W + 2);
            int gy = ty0 - 1 + r;
            int gx = col - 1;
            float v = 0.f;
            if ((unsigned)gy < (unsigned)H && (unsigned)gx < (unsigned)W)
                v = xb[((size_t)(c0 + cc) * H + gy) * W + gx];
            xs[cc][r][col] = v;
        }

        // ---- stage aggregated weights: sum_k att[k] * weight[k,o,c,tap] ----
        for (int idx = tid; idx < W_ELEMS; idx += 256) {
            int o   = idx / (CC * 9);
            int rem = idx - o * (CC * 9);
            int cc  = rem / 9;
            int tap = rem - cc * 9;
            size_t base = ((size_t)(o0 + o) * C + (c0 + cc)) * 9 + tap;
            float v = a0 * weight[base]
                    + a1 * weight[(size_t)1 * O * C * 9 + base]
                    + a2 * weight[(size_t)2 * O * C * 9 + base]
                    + a3 * weight[(size_t)3 * O * C * 9 + base];
            ws_s[o][cc][tap] = v;
        }

        __syncthreads();

        // ---- compute ----
        #pragma unroll
        for (int cc = 0; cc < CC; ++cc) {
            // x neighborhood: 3 rows x 10 cols (8 pixels + 2 halo)
            float xv[3][10];
            #pragma unroll
            for (int dy = 0; dy < 3; ++dy)
                #pragma unroll
                for (int j = 0; j < 10; ++j)
                    xv[dy][j] = xs[cc][ty + dy][8 * tx + j];

            #pragma unroll
            for (int o = 0; o < OT; ++o) {
                float4 w0 = *(const float4*)&ws_s[o][cc][0];  // taps 0..3
                float4 w1 = *(const float4*)&ws_s[o][cc][4];  // taps 4..7
                float  w8 = ws_s[o][cc][8];                   // tap 8
                #pragma unroll
                for (int p = 0; p < PX; ++p) {
                    float s = acc[o][p];
                    s = fmaf(xv[0][p + 0], w0.x, s);
                    s = fmaf(xv[0][p + 1], w0.y, s);
                    s = fmaf(xv[0][p + 2], w0.z, s);
                    s = fmaf(xv[1][p + 0], w0.w, s);
                    s = fmaf(xv[1][p + 1], w1.x, s);
                    s = fmaf(xv[1][p + 2], w1.y, s);
                    s = fmaf(xv[2][p + 0], w1.z, s);
                    s = fmaf(xv[2][p + 1], w1.w, s);
                    s = fmaf(xv[2][p + 2], w8, s);
                    acc[o][p] = s;
                }
            }
        }
    }

    // ---- epilogue: add aggregated bias, store ----
    const int oy = ty0 + ty;
    const int ox = 8 * tx;
    #pragma unroll
    for (int o = 0; o < OT; ++o) {
        float ab = a0 * bias[0 * O + o0 + o]
                 + a1 * bias[1 * O + o0 + o]
                 + a2 * bias[2 * O + o0 + o]
                 + a3 * bias[3 * O + o0 + o];
        float4 v0 = make_float4(acc[o][0] + ab, acc[o][1] + ab,
                                acc[o][2] + ab, acc[o][3] + ab);
        float4 v1 = make_float4(acc[o][4] + ab, acc[o][5] + ab,
                                acc[o][6] + ab, acc[o][7] + ab);
        float* op = out + (((size_t)b * O + (o0 + o)) * H + oy) * W + ox;
        *(float4*)(op)     = v0;
        *(float4*)(op + 4) = v1;
    }
}

// ---------------------------------------------------------------------------
extern "C" void kernel_launch(void* const* d_in, const int* in_sizes, int n_in,
                              void* d_out, int out_size, void* d_ws, size_t ws_size,
                              hipStream_t stream) {
    const float* x      = (const float*)d_in[0];
    const float* w_fc1  = (const float*)d_in[1];
    const float* w_fc2  = (const float*)d_in[2];
    const float* b_fc2  = (const float*)d_in[3];
    const float* weight = (const float*)d_in[4];
    const float* bias   = (const float*)d_in[5];
    float* out = (float*)d_out;

    float* pooled = (float*)d_ws;            // B*C floats
    float* att    = pooled + B * C;          // B*K floats

    pool_kernel<<<dim3(B * C), dim3(256), 0, stream>>>(x, pooled);
    attention_kernel<<<dim3(B), dim3(128), 0, stream>>>(pooled, w_fc1, w_fc2, b_fc2, att);

    dim3 grid(H / TILE_H, O / OT, B);        // (2, 32, 16)
    conv_kernel<<<grid, dim3(256), 0, stream>>>(x, weight, bias, att, out);
}

// Round 2
// 338.496 us; speedup vs baseline: 6.6196x; 6.6196x over previous
//
#include <hip/hip_runtime.h>
#include <math.h>

// Problem constants (from reference setup_inputs)
constexpr int B   = 16;
constexpr int C   = 256;
constexpr int H   = 64;
constexpr int W   = 64;
constexpr int K   = 4;
constexpr int O   = 256;
constexpr int HID = 65;            // int(256*0.25)+1
constexpr float TEMP = 34.0f;

typedef __bf16 bf16x8 __attribute__((ext_vector_type(8)));
typedef float  f32x4  __attribute__((ext_vector_type(4)));
typedef unsigned short ushort_t;

__device__ inline ushort_t f2bf(float f) {
    union { float f; unsigned u; } v; v.f = f;
    unsigned u = v.u;
    u += 0x7FFF + ((u >> 16) & 1);       // round-to-nearest-even
    return (ushort_t)(u >> 16);
}

// ---------------------------------------------------------------------------
// Kernel 1: global average pool  pooled[b,c] = mean(x[b,c,:,:])
// ---------------------------------------------------------------------------
__global__ void pool_kernel(const float* __restrict__ x, float* __restrict__ pooled) {
    const int bc = blockIdx.x;
    const float4* p4 = (const float4*)(x + (size_t)bc * (H * W));
    const int tid = threadIdx.x;
    float s = 0.f;
    #pragma unroll
    for (int i = 0; i < (H * W / 4) / 256; ++i) {
        float4 v = p4[tid + i * 256];
        s += (v.x + v.y) + (v.z + v.w);
    }
    #pragma unroll
    for (int off = 32; off > 0; off >>= 1) s += __shfl_down(s, off, 64);
    __shared__ float red[4];
    if ((tid & 63) == 0) red[tid >> 6] = s;
    __syncthreads();
    if (tid == 0) {
        float t = (red[0] + red[1]) + (red[2] + red[3]);
        pooled[bc] = t * (1.0f / (H * W));
    }
}

// ---------------------------------------------------------------------------
// Kernel 2: attention  att[b,k] = softmax_k( (relu(pooled@W1^T)@W2^T + b2)/T )
// ---------------------------------------------------------------------------
__global__ void attention_kernel(const float* __restrict__ pooled,
                                 const float* __restrict__ w_fc1,
                                 const float* __restrict__ w_fc2,
                                 const float* __restrict__ b_fc2,
                                 float* __restrict__ att) {
    const int b = blockIdx.x;
    const int tid = threadIdx.x;
    __shared__ float pool_s[C];
    __shared__ float h_s[HID];
    __shared__ float logit_s[K];

    for (int i = tid; i < C; i += blockDim.x) pool_s[i] = pooled[b * C + i];
    __syncthreads();

    for (int j = tid; j < HID; j += blockDim.x) {
        const float* wr = w_fc1 + (size_t)j * C;
        float s = 0.f;
        #pragma unroll 4
        for (int c = 0; c < C; ++c) s += pool_s[c] * wr[c];
        h_s[j] = fmaxf(s, 0.f);
    }
    __syncthreads();

    if (tid < K) {
        const float* wr = w_fc2 + (size_t)tid * HID;
        float s = b_fc2[tid];
        for (int j = 0; j < HID; ++j) s += h_s[j] * wr[j];
        logit_s[tid] = s * (1.0f / TEMP);
    }
    __syncthreads();

    if (tid == 0) {
        float m = fmaxf(fmaxf(logit_s[0], logit_s[1]), fmaxf(logit_s[2], logit_s[3]));
        float e0 = expf(logit_s[0] - m);
        float e1 = expf(logit_s[1] - m);
        float e2 = expf(logit_s[2] - m);
        float e3 = expf(logit_s[3] - m);
        float inv = 1.0f / (e0 + e1 + e2 + e3);
        att[b * K + 0] = e0 * inv;
        att[b * K + 1] = e1 * inv;
        att[b * K + 2] = e2 * inv;
        att[b * K + 3] = e3 * inv;
    }
}

// ---------------------------------------------------------------------------
// Kernel 2.5: aggregate expert weights per sample, cast to bf16.
// wagg[b][t][o][c] = bf16( sum_k att[b][k] * weight[k][o][c][t] )
// grid = O blocks (one per o), 256 threads (one per c). Each thread keeps the
// 4x9 weight taps in registers and loops over the 16 samples.
// ---------------------------------------------------------------------------
__global__ void wagg_kernel(const float* __restrict__ weight,
                            const float* __restrict__ att,
                            ushort_t* __restrict__ wagg) {
    const int o = blockIdx.x;
    const int c = threadIdx.x;
    __shared__ float att_s[B * K];
    if (c < B * K) att_s[c] = att[c];

    float w[K][9];
    #pragma unroll
    for (int k = 0; k < K; ++k) {
        const float* src = weight + (((size_t)(k * O + o)) * C + c) * 9;
        #pragma unroll
        for (int t = 0; t < 9; ++t) w[k][t] = src[t];
    }
    __syncthreads();

    for (int b = 0; b < B; ++b) {
        const float a0 = att_s[b * K + 0];
        const float a1 = att_s[b * K + 1];
        const float a2 = att_s[b * K + 2];
        const float a3 = att_s[b * K + 3];
        #pragma unroll
        for (int t = 0; t < 9; ++t) {
            float s = a0 * w[0][t] + a1 * w[1][t] + a2 * w[2][t] + a3 * w[3][t];
            wagg[(((size_t)(b * 9 + t)) * O + o) * C + c] = f2bf(s);
        }
    }
}

// ---------------------------------------------------------------------------
// Kernel 3 (MFMA): implicit-GEMM dynamic conv.
// Per sample b: out[o][p] = sum_{t,c} wagg[b][t][o][c] * xshift_t[c][p] + bias
// Block: 128 o x 128 px (2 rows of 64). 4 waves in 2x2; each wave 4x4 tiles of
// mfma_f32_16x16x32_bf16. K-loop: 4 c-chunks(64) x 9 taps x 2 k-steps.
// x staged once per c-chunk, transposed to [row][col][c] (c contiguous) so tap
// shifts are pure LDS address offsets and B-frags are single b128 reads.
// ---------------------------------------------------------------------------
__global__ __launch_bounds__(256, 2)
void conv_mfma_kernel(const float* __restrict__ x,
                      const ushort_t* __restrict__ wagg,
                      const float* __restrict__ bias,
                      const float* __restrict__ att,
                      float* __restrict__ out) {
    const int o0 = blockIdx.x * 128;     // 0 or 128
    const int pt = blockIdx.y;           // 0..31 -> rows y0, y0+1
    const int b  = blockIdx.z;
    const int y0 = pt * 2;

    const int tid  = threadIdx.x;
    const int lane = tid & 63;
    const int wid  = tid >> 6;           // 0..3
    const int wm   = wid & 1;            // m half
    const int wn   = wid >> 1;           // n half (row within pixel pair)
    const int n16  = lane & 15;
    const int q    = lane >> 4;          // 0..3

    // c-stride 72 (pad 8): keeps every b128 16B-aligned, uniform bank use.
    __shared__ ushort_t xls[4][66][72];      // [row r][col 0..65][c]  38016 B
    __shared__ ushort_t aws[2][128][72];     // [buf][o][c]            36864 B

    f32x4 acc[4][4];
    #pragma unroll
    for (int mi = 0; mi < 4; ++mi)
        #pragma unroll
        for (int ni = 0; ni < 4; ++ni) {
            f32x4 z = {0.f, 0.f, 0.f, 0.f};
            acc[mi][ni] = z;
        }

    // staging roles
    const int sc = tid & 63;             // channel within chunk
    const int sr = tid >> 6;             // halo row 0..3
    const int so = tid >> 1;             // o row for A staging
    const int sh = tid & 1;              // which 32-c half

    const ushort_t* wb = wagg + (size_t)b * 9 * O * C;

    auto stage_x = [&](int c0) {
        const int gy = y0 - 1 + sr;
        ushort_t* dst = &xls[sr][0][sc];            // col stride 72
        if ((unsigned)gy < (unsigned)H) {
            const float4* src = (const float4*)(x + (((size_t)(b * C + c0 + sc)) * H + gy) * W);
            dst[0] = 0; dst[65 * 72] = 0;           // col halos
            #pragma unroll
            for (int i = 0; i < 16; ++i) {
                float4 v = src[i];
                dst[(1 + 4 * i + 0) * 72] = f2bf(v.x);
                dst[(1 + 4 * i + 1) * 72] = f2bf(v.y);
                dst[(1 + 4 * i + 2) * 72] = f2bf(v.z);
                dst[(1 + 4 * i + 3) * 72] = f2bf(v.w);
            }
        } else {
            #pragma unroll
            for (int col = 0; col < 66; ++col) dst[col * 72] = 0;
        }
    };

    auto load_a = [&](int c0, int t, uint4* pre) {
        const uint4* s = (const uint4*)(wb + ((size_t)t * O + o0 + so) * C + c0 + sh * 32);
        pre[0] = s[0]; pre[1] = s[1]; pre[2] = s[2]; pre[3] = s[3];
    };
    auto write_a = [&](int bufsel, const uint4* pre) {
        uint4* d = (uint4*)&aws[bufsel][so][sh * 32];
        d[0] = pre[0]; d[1] = pre[1]; d[2] = pre[2]; d[3] = pre[3];
    };

    auto compute_tap = [&](int bufsel, int t) {
        const int dy = t / 3, dx = t % 3;
        const int r = wn + dy;
        #pragma unroll
        for (int ks = 0; ks < 2; ++ks) {
            bf16x8 af[4], bfr[4];
            #pragma unroll
            for (int mi = 0; mi < 4; ++mi)
                af[mi] = *(const bf16x8*)&aws[bufsel][wm * 64 + mi * 16 + n16][ks * 32 + q * 8];
            #pragma unroll
            for (int ni = 0; ni < 4; ++ni) {
                const int col = ni * 16 + n16 + dx;
                bfr[ni] = *(const bf16x8*)&xls[r][col][ks * 32 + q * 8];
            }
            #pragma unroll
            for (int mi = 0; mi < 4; ++mi)
                #pragma unroll
                for (int ni = 0; ni < 4; ++ni)
                    acc[mi][ni] = __builtin_amdgcn_mfma_f32_16x16x32_bf16(
                        af[mi], bfr[ni], acc[mi][ni], 0, 0, 0);
        }
    };

    // prologue
    uint4 pre[4];
    stage_x(0);
    load_a(0, 0, pre);
    write_a(0, pre);
    __syncthreads();

    int buf = 0;
    for (int ci = 0; ci < 4; ++ci) {
        const int c0 = ci * 64;
        for (int t = 0; t < 9; ++t) {
            const bool have_next = (t < 8) || (ci < 3);
            if (t < 8)        load_a(c0, t + 1, pre);       // prefetch next tap's A
            else if (ci < 3)  load_a(c0 + 64, 0, pre);      // prefetch next chunk tap 0

            compute_tap(buf, t);

            if (have_next) write_a(buf ^ 1, pre);
            __syncthreads();
            if (t == 8 && ci < 3) {                          // restage x for next chunk
                stage_x(c0 + 64);
                __syncthreads();
            }
            buf ^= 1;
        }
    }

    // epilogue: bias (fp32) + store
    const float a0 = att[b * K + 0];
    const float a1 = att[b * K + 1];
    const float a2 = att[b * K + 2];
    const float a3 = att[b * K + 3];
    const int y = y0 + wn;
    #pragma unroll
    for (int mi = 0; mi < 4; ++mi) {
        #pragma unroll
        for (int rr = 0; rr < 4; ++rr) {
            const int o = o0 + wm * 64 + mi * 16 + q * 4 + rr;
            const float ab = a0 * bias[0 * O + o] + a1 * bias[1 * O + o]
                           + a2 * bias[2 * O + o] + a3 * bias[3 * O + o];
            #pragma unroll
            for (int ni = 0; ni < 4; ++ni) {
                const int nl = ni * 16 + n16;
                out[(((size_t)(b * O + o)) * H + y) * W + nl] = acc[mi][ni][rr] + ab;
            }
        }
    }
}

// ---------------------------------------------------------------------------
// Fallback fp32 direct conv (round-1, known-correct) for small ws_size.
// ---------------------------------------------------------------------------
constexpr int TILE_H = 32;
constexpr int TILE_W = 64;
constexpr int CCF    = 4;
constexpr int OT     = 8;
constexpr int PX     = 8;
constexpr int XS_STRIDE = TILE_W + 2 + 1;

__global__ __launch_bounds__(256, 2)
void conv_kernel(const float* __restrict__ x,
                 const float* __restrict__ weight,
                 const float* __restrict__ bias,
                 const float* __restrict__ att,
                 float* __restrict__ out) {
    const int tile_y = blockIdx.x;
    const int o0     = blockIdx.y * OT;
    const int b      = blockIdx.z;
    const int tid = threadIdx.x;
    const int tx  = tid & 7;
    const int ty  = tid >> 3;
    const int ty0 = tile_y * TILE_H;

    __shared__ __align__(16) float xs[CCF][TILE_H + 2][XS_STRIDE];
    __shared__ __align__(16) float ws_s[OT][CCF][12];

    const float a0 = att[b * K + 0], a1 = att[b * K + 1];
    const float a2 = att[b * K + 2], a3 = att[b * K + 3];

    float acc[OT][PX];
    #pragma unroll
    for (int o = 0; o < OT; ++o)
        #pragma unroll
        for (int p = 0; p < PX; ++p) acc[o][p] = 0.f;

    const float* xb = x + (size_t)b * C * H * W;
    constexpr int X_ELEMS = CCF * (TILE_H + 2) * (TILE_W + 2);
    constexpr int W_ELEMS = OT * CCF * 9;

    for (int c0 = 0; c0 < C; c0 += CCF) {
        __syncthreads();
        for (int idx = tid; idx < X_ELEMS; idx += 256) {
            int cc  = idx / ((TILE_H + 2) * (TILE_W + 2));
            int rem = idx - cc * ((TILE_H + 2) * (TILE_W + 2));
            int r   = rem / (TILE_W + 2);
            int col = rem - r * (TILE_W + 2);
            int gy = ty0 - 1 + r;
            int gx = col - 1;
            float v = 0.f;
            if ((unsigned)gy < (unsigned)H && (unsigned)gx < (unsigned)W)
                v = xb[((size_t)(c0 + cc) * H + gy) * W + gx];
            xs[cc][r][col] = v;
        }
        for (int idx = tid; idx < W_ELEMS; idx += 256) {
            int o   = idx / (CCF * 9);
            int rem = idx - o * (CCF * 9);
            int cc  = rem / 9;
            int tap = rem - cc * 9;
            size_t base = ((size_t)(o0 + o) * C + (c0 + cc)) * 9 + tap;
            float v = a0 * weight[base]
                    + a1 * weight[(size_t)1 * O * C * 9 + base]
                    + a2 * weight[(size_t)2 * O * C * 9 + base]
                    + a3 * weight[(size_t)3 * O * C * 9 + base];
            ws_s[o][cc][tap] = v;
        }
        __syncthreads();
        #pragma unroll
        for (int cc = 0; cc < CCF; ++cc) {
            float xv[3][10];
            #pragma unroll
            for (int dy = 0; dy < 3; ++dy)
                #pragma unroll
                for (int j = 0; j < 10; ++j)
                    xv[dy][j] = xs[cc][ty + dy][8 * tx + j];
            #pragma unroll
            for (int o = 0; o < OT; ++o) {
                float4 w0 = *(const float4*)&ws_s[o][cc][0];
                float4 w1 = *(const float4*)&ws_s[o][cc][4];
                float  w8 = ws_s[o][cc][8];
                #pragma unroll
                for (int p = 0; p < PX; ++p) {
                    float s = acc[o][p];
                    s = fmaf(xv[0][p + 0], w0.x, s);
                    s = fmaf(xv[0][p + 1], w0.y, s);
                    s = fmaf(xv[0][p + 2], w0.z, s);
                    s = fmaf(xv[1][p + 0], w0.w, s);
                    s = fmaf(xv[1][p + 1], w1.x, s);
                    s = fmaf(xv[1][p + 2], w1.y, s);
                    s = fmaf(xv[2][p + 0], w1.z, s);
                    s = fmaf(xv[2][p + 1], w1.w, s);
                    s = fmaf(xv[2][p + 2], w8, s);
                    acc[o][p] = s;
                }
            }
        }
    }
    const int oy = ty0 + ty;
    const int ox = 8 * tx;
    #pragma unroll
    for (int o = 0; o < OT; ++o) {
        float ab = a0 * bias[0 * O + o0 + o] + a1 * bias[1 * O + o0 + o]
                 + a2 * bias[2 * O + o0 + o] + a3 * bias[3 * O + o0 + o];
        float4 v0 = make_float4(acc[o][0] + ab, acc[o][1] + ab, acc[o][2] + ab, acc[o][3] + ab);
        float4 v1 = make_float4(acc[o][4] + ab, acc[o][5] + ab, acc[o][6] + ab, acc[o][7] + ab);
        float* op = out + (((size_t)b * O + (o0 + o)) * H + oy) * W + ox;
        *(float4*)(op)     = v0;
        *(float4*)(op + 4) = v1;
    }
}

// ---------------------------------------------------------------------------
extern "C" void kernel_launch(void* const* d_in, const int* in_sizes, int n_in,
                              void* d_out, int out_size, void* d_ws, size_t ws_size,
                              hipStream_t stream) {
    const float* x      = (const float*)d_in[0];
    const float* w_fc1  = (const float*)d_in[1];
    const float* w_fc2  = (const float*)d_in[2];
    const float* b_fc2  = (const float*)d_in[3];
    const float* weight = (const float*)d_in[4];
    const float* bias   = (const float*)d_in[5];
    float* out = (float*)d_out;

    float* pooled = (float*)d_ws;                        // B*C floats (16 KB)
    float* att    = pooled + B * C;                      // B*K floats
    ushort_t* wagg = (ushort_t*)((char*)d_ws + 32 * 1024);
    const size_t needed = 32 * 1024 + (size_t)B * 9 * O * C * sizeof(ushort_t);

    pool_kernel<<<dim3(B * C), dim3(256), 0, stream>>>(x, pooled);
    attention_kernel<<<dim3(B), dim3(128), 0, stream>>>(pooled, w_fc1, w_fc2, b_fc2, att);

    if (ws_size >= needed) {
        wagg_kernel<<<dim3(O), dim3(256), 0, stream>>>(weight, att, wagg);
        dim3 grid(O / 128, (H * W) / 128, B);            // (2, 32, 16)
        conv_mfma_kernel<<<grid, dim3(256), 0, stream>>>(x, wagg, bias, att, out);
    } else {
        dim3 grid(H / TILE_H, O / OT, B);                // (2, 32, 16)
        conv_kernel<<<grid, dim3(256), 0, stream>>>(x, weight, bias, att, out);
    }
}

// Round 3
// 227.941 us; speedup vs baseline: 9.8303x; 1.4850x over previous
//
#include <hip/hip_runtime.h>
#include <math.h>

// Problem constants
constexpr int B   = 16;
constexpr int C   = 256;
constexpr int H   = 64;
constexpr int W   = 64;
constexpr int K   = 4;
constexpr int O   = 256;
constexpr int HID = 65;
constexpr float TEMP = 34.0f;

typedef __bf16 bf16x8 __attribute__((ext_vector_type(8)));
typedef float  f32x16 __attribute__((ext_vector_type(16)));
typedef unsigned short ushort_t;

__device__ inline ushort_t f2bf(float f) {
    union { float f; unsigned u; } v; v.f = f;
    unsigned u = v.u;
    u += 0x7FFF + ((u >> 16) & 1);       // RNE
    return (ushort_t)(u >> 16);
}

__device__ inline void gl2lds16(const void* g, void* l) {
    __builtin_amdgcn_global_load_lds(
        (const __attribute__((address_space(1))) unsigned int*)g,
        (__attribute__((address_space(3))) unsigned int*)l, 16, 0, 0);
}

// ---------------------------------------------------------------------------
// Fused transpose + pool.  xT[b][ci][y][col][cc16] (bf16) ; pooled[b][c] via
// atomicAdd of per-block partial means.  grid (ci=16, yg=4, b=16), 256 thr.
// ---------------------------------------------------------------------------
__global__ void tp_kernel(const float* __restrict__ x,
                          ushort_t* __restrict__ xT,
                          float* __restrict__ pooled) {
    const int ci = blockIdx.x, yg = blockIdx.y, b = blockIdx.z;
    const int tid = threadIdx.x;
    const int cc = tid >> 4;             // 0..15
    const int yy = tid & 15;             // 0..15
    const int y  = yg * 16 + yy;
    const int c  = ci * 16 + cc;

    __shared__ ushort_t t_lds[16 * 1040];    // [yy][col(64) pad->65][cc16]
    __shared__ float pool_l[16];
    if (tid < 16) pool_l[tid] = 0.f;
    __syncthreads();

    const float4* src = (const float4*)(x + (((size_t)b * C + c) * H + y) * W);
    float s = 0.f;
    #pragma unroll
    for (int i = 0; i < 16; ++i) {
        float4 v = src[i];
        s += (v.x + v.y) + (v.z + v.w);
        ushort_t* d = &t_lds[yy * 1040 + (4 * i) * 16 + cc];
        d[0]  = f2bf(v.x);
        d[16] = f2bf(v.y);
        d[32] = f2bf(v.z);
        d[48] = f2bf(v.w);
    }
    atomicAdd(&pool_l[cc], s);
    __syncthreads();
    if (tid < 16)
        atomicAdd(&pooled[b * C + ci * 16 + tid], pool_l[tid] * (1.0f / (H * W)));

    // store phase: per yy, 2 KB contiguous
    const int w    = tid >> 6;
    const int lane = tid & 63;
    const int col  = lane >> 1;
    const int half = lane & 1;
    #pragma unroll
    for (int q = 0; q < 4; ++q) {
        const int y2 = w * 4 + q;
        ushort_t* gbase = xT + ((((size_t)b * 16 + ci) * 64 + (yg * 16 + y2)) * 64) * 16;
        #pragma unroll
        for (int sseg = 0; sseg < 2; ++sseg) {
            uint4 v = *(const uint4*)&t_lds[y2 * 1040 + (sseg * 32 + col) * 16 + half * 8];
            *(uint4*)(gbase + sseg * 512 + lane * 8) = v;
        }
    }
}

// ---------------------------------------------------------------------------
// Attention (pooled must be complete).  grid=B, 128 thr.
// ---------------------------------------------------------------------------
__global__ void attention_kernel(const float* __restrict__ pooled,
                                 const float* __restrict__ w_fc1,
                                 const float* __restrict__ w_fc2,
                                 const float* __restrict__ b_fc2,
                                 float* __restrict__ att) {
    const int b = blockIdx.x;
    const int tid = threadIdx.x;
    __shared__ float pool_s[C];
    __shared__ float h_s[HID];
    __shared__ float logit_s[K];

    for (int i = tid; i < C; i += blockDim.x) pool_s[i] = pooled[b * C + i];
    __syncthreads();
    for (int j = tid; j < HID; j += blockDim.x) {
        const float* wr = w_fc1 + (size_t)j * C;
        float s = 0.f;
        #pragma unroll 4
        for (int c = 0; c < C; ++c) s += pool_s[c] * wr[c];
        h_s[j] = fmaxf(s, 0.f);
    }
    __syncthreads();
    if (tid < K) {
        const float* wr = w_fc2 + (size_t)tid * HID;
        float s = b_fc2[tid];
        for (int j = 0; j < HID; ++j) s += h_s[j] * wr[j];
        logit_s[tid] = s * (1.0f / TEMP);
    }
    __syncthreads();
    if (tid == 0) {
        float m = fmaxf(fmaxf(logit_s[0], logit_s[1]), fmaxf(logit_s[2], logit_s[3]));
        float e0 = expf(logit_s[0] - m), e1 = expf(logit_s[1] - m);
        float e2 = expf(logit_s[2] - m), e3 = expf(logit_s[3] - m);
        float inv = 1.0f / (e0 + e1 + e2 + e3);
        att[b * K + 0] = e0 * inv; att[b * K + 1] = e1 * inv;
        att[b * K + 2] = e2 * inv; att[b * K + 3] = e3 * inv;
    }
}

// ---------------------------------------------------------------------------
// Weight aggregation -> bf16, emitted in MFMA A-fragment lane order:
// wagg_sw[b][ci16][t9][mi8][lane64][j8],  lane=(c>>3 &1)*32 + (o&31),
// j=c&7, ci=c>>4.   grid=O blocks, 256 thr (oct=c-octet, bg=b-pair).
// ---------------------------------------------------------------------------
__global__ void wagg_kernel(const float* __restrict__ weight,
                            const float* __restrict__ att,
                            ushort_t* __restrict__ wagg_sw) {
    const int o = blockIdx.x;
    const int tid = threadIdx.x;
    const int oct = tid >> 3;            // 0..31  (c = oct*8 .. +8)
    const int bg  = tid & 7;             // b pair

    __shared__ float att_s[B * K];
    if (tid < B * K) att_s[tid] = att[tid];
    __syncthreads();

    const int mi   = o >> 5;
    const int lm   = o & 31;
    const int ci   = oct >> 1;
    const int half = oct & 1;
    const int lane = half * 32 + lm;

    for (int t = 0; t < 9; ++t) {
        float w0[8], w1[8], w2[8], w3[8];
        #pragma unroll
        for (int j = 0; j < 8; ++j) {
            const size_t cidx = (size_t)(oct * 8 + j) * 9 + t;
            w0[j] = weight[((size_t)(0 * O + o) * C) * 9 + cidx];
            w1[j] = weight[((size_t)(1 * O + o) * C) * 9 + cidx];
            w2[j] = weight[((size_t)(2 * O + o) * C) * 9 + cidx];
            w3[j] = weight[((size_t)(3 * O + o) * C) * 9 + cidx];
        }
        #pragma unroll
        for (int bb = 0; bb < 2; ++bb) {
            const int b = bg * 2 + bb;
            const float a0 = att_s[b * K + 0], a1 = att_s[b * K + 1];
            const float a2 = att_s[b * K + 2], a3 = att_s[b * K + 3];
            union { ushort_t u[8]; uint4 v; } pk;
            #pragma unroll
            for (int j = 0; j < 8; ++j)
                pk.u[j] = f2bf(a0 * w0[j] + a1 * w1[j] + a2 * w2[j] + a3 * w3[j]);
            size_t idx = ((((size_t)b * 16 + ci) * 9 + t) * 8 + mi) * 512 + lane * 8;
            *(uint4*)&wagg_sw[idx] = pk.v;
        }
    }
}

// ---------------------------------------------------------------------------
// MFMA conv: 32x32x16, wave tile 4m x 2n, block = 128 o x (4 rows x 64 cols).
// K-chunks of 16 c x 9 taps staged together via global_load_lds. 2 barriers
// per chunk (32 total).  grid (b=16, yt=16, oz=2) -> b%8 XCD confinement.
// ---------------------------------------------------------------------------
__global__ __launch_bounds__(256, 2)
void conv_mfma_kernel(const ushort_t* __restrict__ xT,
                      const ushort_t* __restrict__ wagg_sw,
                      const float* __restrict__ bias,
                      const float* __restrict__ att,
                      float* __restrict__ out) {
    const int b  = blockIdx.x;
    const int yt = blockIdx.y;
    const int oz = blockIdx.z;
    const int y0 = yt * 4;

    const int tid  = threadIdx.x;
    const int lane = tid & 63;
    const int wid  = tid >> 6;           // wave -> output row y0+wid
    const int n16  = lane & 31;
    const int khalf = lane >> 5;

    __shared__ __align__(16) ushort_t A_lds[9 * 4 * 512];   // [t][a][lane*8+j] 36,864 B
    __shared__ __align__(16) ushort_t x_lds[6 * 66 * 16];   // [r][col66][cc16] 12,672 B

    // zero x halos (OOB rows + col 0/65 never overwritten)
    for (int i = tid; i < 6 * 66 * 16; i += 256) x_lds[i] = 0;

    f32x16 acc[4][2];
    #pragma unroll
    for (int a = 0; a < 4; ++a)
        #pragma unroll
        for (int ni = 0; ni < 2; ++ni)
            acc[a][ni] = (f32x16)(0.f);

    for (int ci = 0; ci < 16; ++ci) {
        __syncthreads();   // previous chunk's LDS reads complete

        // stage A: 36 x 1KB
        for (int i = wid; i < 36; i += 4) {
            const int t = i >> 2, a = i & 3;
            const ushort_t* g = wagg_sw
                + ((((size_t)b * 16 + ci) * 9 + t) * 8 + (oz * 4 + a)) * 512 + lane * 8;
            gl2lds16(g, &A_lds[(t * 4 + a) * 512]);
        }
        // stage x: 6 rows x 2KB
        for (int r = wid; r < 6; r += 4) {
            const int y = y0 - 1 + r;
            if ((unsigned)y < (unsigned)H) {
                const ushort_t* gr = xT + ((((size_t)b * 16 + ci) * 64 + y) * 64) * 16;
                #pragma unroll
                for (int h = 0; h < 2; ++h)
                    gl2lds16(gr + h * 512 + lane * 8,
                             &x_lds[r * (66 * 16) + 16 + h * 512]);
            }
        }

        __syncthreads();   // drain vmcnt -> staged data visible

        #pragma unroll
        for (int dy = 0; dy < 3; ++dy) {
            const int r = wid + dy;
            #pragma unroll
            for (int dx = 0; dx < 3; ++dx) {
                const int t = dy * 3 + dx;
                bf16x8 bf[2];
                #pragma unroll
                for (int ni = 0; ni < 2; ++ni)
                    bf[ni] = *(const bf16x8*)&x_lds[r * (66 * 16)
                              + (ni * 32 + n16 + dx) * 16 + khalf * 8];
                #pragma unroll
                for (int a = 0; a < 4; ++a) {
                    bf16x8 af = *(const bf16x8*)&A_lds[(t * 4 + a) * 512 + lane * 8];
                    acc[a][0] = __builtin_amdgcn_mfma_f32_32x32x16_bf16(af, bf[0], acc[a][0], 0, 0, 0);
                    acc[a][1] = __builtin_amdgcn_mfma_f32_32x32x16_bf16(af, bf[1], acc[a][1], 0, 0, 0);
                }
            }
        }
    }

    // epilogue: aggregated bias via LDS (reuse A_lds), then store
    __syncthreads();
    float* aggb = (float*)A_lds;
    if (tid < 128) {
        const int o = oz * 128 + tid;
        aggb[tid] = att[b * K + 0] * bias[0 * O + o] + att[b * K + 1] * bias[1 * O + o]
                  + att[b * K + 2] * bias[2 * O + o] + att[b * K + 3] * bias[3 * O + o];
    }
    __syncthreads();

    const int y = y0 + wid;
    #pragma unroll
    for (int a = 0; a < 4; ++a) {
        #pragma unroll
        for (int ni = 0; ni < 2; ++ni) {
            #pragma unroll
            for (int reg = 0; reg < 16; ++reg) {
                const int row = (reg & 3) + 8 * (reg >> 2) + 4 * khalf;
                const int ol  = a * 32 + row;
                out[(((size_t)b * O + oz * 128 + ol) * H + y) * W + ni * 32 + n16]
                    = acc[a][ni][reg] + aggb[ol];
            }
        }
    }
}

// ---------------------------------------------------------------------------
// Fallback fp32 path (round-1, known-correct) if ws too small.
// ---------------------------------------------------------------------------
__global__ void pool_kernel(const float* __restrict__ x, float* __restrict__ pooled) {
    const int bc = blockIdx.x;
    const float4* p4 = (const float4*)(x + (size_t)bc * (H * W));
    const int tid = threadIdx.x;
    float s = 0.f;
    #pragma unroll
    for (int i = 0; i < (H * W / 4) / 256; ++i) {
        float4 v = p4[tid + i * 256];
        s += (v.x + v.y) + (v.z + v.w);
    }
    #pragma unroll
    for (int off = 32; off > 0; off >>= 1) s += __shfl_down(s, off, 64);
    __shared__ float red[4];
    if ((tid & 63) == 0) red[tid >> 6] = s;
    __syncthreads();
    if (tid == 0) pooled[bc] = ((red[0] + red[1]) + (red[2] + red[3])) * (1.0f / (H * W));
}

constexpr int TILE_H = 32;
constexpr int TILE_W = 64;
constexpr int CCF = 4, OT = 8, PX = 8;
constexpr int XS_STRIDE = TILE_W + 3;

__global__ __launch_bounds__(256, 2)
void conv_kernel(const float* __restrict__ x, const float* __restrict__ weight,
                 const float* __restrict__ bias, const float* __restrict__ att,
                 float* __restrict__ out) {
    const int tile_y = blockIdx.x, o0 = blockIdx.y * OT, b = blockIdx.z;
    const int tid = threadIdx.x, tx = tid & 7, ty = tid >> 3, ty0 = tile_y * TILE_H;
    __shared__ __align__(16) float xs[CCF][TILE_H + 2][XS_STRIDE];
    __shared__ __align__(16) float ws_s[OT][CCF][12];
    const float a0 = att[b * K + 0], a1 = att[b * K + 1];
    const float a2 = att[b * K + 2], a3 = att[b * K + 3];
    float acc[OT][PX];
    #pragma unroll
    for (int o = 0; o < OT; ++o)
        #pragma unroll
        for (int p = 0; p < PX; ++p) acc[o][p] = 0.f;
    const float* xb = x + (size_t)b * C * H * W;
    constexpr int X_ELEMS = CCF * (TILE_H + 2) * (TILE_W + 2);
    constexpr int W_ELEMS = OT * CCF * 9;
    for (int c0 = 0; c0 < C; c0 += CCF) {
        __syncthreads();
        for (int idx = tid; idx < X_ELEMS; idx += 256) {
            int cc = idx / ((TILE_H + 2) * (TILE_W + 2));
            int rem = idx - cc * ((TILE_H + 2) * (TILE_W + 2));
            int r = rem / (TILE_W + 2), col = rem - r * (TILE_W + 2);
            int gy = ty0 - 1 + r, gx = col - 1;
            float v = 0.f;
            if ((unsigned)gy < (unsigned)H && (unsigned)gx < (unsigned)W)
                v = xb[((size_t)(c0 + cc) * H + gy) * W + gx];
            xs[cc][r][col] = v;
        }
        for (int idx = tid; idx < W_ELEMS; idx += 256) {
            int o = idx / (CCF * 9), rem = idx - o * (CCF * 9);
            int cc = rem / 9, tap = rem - cc * 9;
            size_t base = ((size_t)(o0 + o) * C + (c0 + cc)) * 9 + tap;
            ws_s[o][cc][tap] = a0 * weight[base] + a1 * weight[(size_t)1 * O * C * 9 + base]
                             + a2 * weight[(size_t)2 * O * C * 9 + base]
                             + a3 * weight[(size_t)3 * O * C * 9 + base];
        }
        __syncthreads();
        #pragma unroll
        for (int cc = 0; cc < CCF; ++cc) {
            float xv[3][10];
            #pragma unroll
            for (int dy = 0; dy < 3; ++dy)
                #pragma unroll
                for (int j = 0; j < 10; ++j) xv[dy][j] = xs[cc][ty + dy][8 * tx + j];
            #pragma unroll
            for (int o = 0; o < OT; ++o) {
                float4 w0 = *(const float4*)&ws_s[o][cc][0];
                float4 w1 = *(const float4*)&ws_s[o][cc][4];
                float w8 = ws_s[o][cc][8];
                #pragma unroll
                for (int p = 0; p < PX; ++p) {
                    float s = acc[o][p];
                    s = fmaf(xv[0][p + 0], w0.x, s); s = fmaf(xv[0][p + 1], w0.y, s);
                    s = fmaf(xv[0][p + 2], w0.z, s); s = fmaf(xv[1][p + 0], w0.w, s);
                    s = fmaf(xv[1][p + 1], w1.x, s); s = fmaf(xv[1][p + 2], w1.y, s);
                    s = fmaf(xv[2][p + 0], w1.z, s); s = fmaf(xv[2][p + 1], w1.w, s);
                    s = fmaf(xv[2][p + 2], w8, s);
                    acc[o][p] = s;
                }
            }
        }
    }
    const int oy = ty0 + ty, ox = 8 * tx;
    #pragma unroll
    for (int o = 0; o < OT; ++o) {
        float ab = a0 * bias[0 * O + o0 + o] + a1 * bias[1 * O + o0 + o]
                 + a2 * bias[2 * O + o0 + o] + a3 * bias[3 * O + o0 + o];
        float4 v0 = make_float4(acc[o][0] + ab, acc[o][1] + ab, acc[o][2] + ab, acc[o][3] + ab);
        float4 v1 = make_float4(acc[o][4] + ab, acc[o][5] + ab, acc[o][6] + ab, acc[o][7] + ab);
        float* op = out + (((size_t)b * O + (o0 + o)) * H + oy) * W + ox;
        *(float4*)(op) = v0; *(float4*)(op + 4) = v1;
    }
}

// ---------------------------------------------------------------------------
extern "C" void kernel_launch(void* const* d_in, const int* in_sizes, int n_in,
                              void* d_out, int out_size, void* d_ws, size_t ws_size,
                              hipStream_t stream) {
    const float* x      = (const float*)d_in[0];
    const float* w_fc1  = (const float*)d_in[1];
    const float* w_fc2  = (const float*)d_in[2];
    const float* b_fc2  = (const float*)d_in[3];
    const float* weight = (const float*)d_in[4];
    const float* bias   = (const float*)d_in[5];
    float* out = (float*)d_out;

    float* pooled = (float*)d_ws;                            // B*C fp32
    float* att    = pooled + B * C;
    ushort_t* wagg_sw = (ushort_t*)((char*)d_ws + 32 * 1024);
    const size_t wagg_bytes = (size_t)B * 16 * 9 * 8 * 512 * 2;      // 18,874,368
    ushort_t* xT = (ushort_t*)((char*)wagg_sw + wagg_bytes);
    const size_t xT_bytes = (size_t)B * 16 * 64 * 64 * 16 * 2;       // 33,554,432
    const size_t needed = 32 * 1024 + wagg_bytes + xT_bytes;

    if (ws_size >= needed) {
        hipMemsetAsync(pooled, 0, B * C * sizeof(float), stream);
        tp_kernel<<<dim3(16, 4, B), dim3(256), 0, stream>>>(x, xT, pooled);
        attention_kernel<<<dim3(B), dim3(128), 0, stream>>>(pooled, w_fc1, w_fc2, b_fc2, att);
        wagg_kernel<<<dim3(O), dim3(256), 0, stream>>>(weight, att, wagg_sw);
        conv_mfma_kernel<<<dim3(B, 16, 2), dim3(256), 0, stream>>>(xT, wagg_sw, bias, att, out);
    } else {
        pool_kernel<<<dim3(B * C), dim3(256), 0, stream>>>(x, pooled);
        attention_kernel<<<dim3(B), dim3(128), 0, stream>>>(pooled, w_fc1, w_fc2, b_fc2, att);
        conv_kernel<<<dim3(H / TILE_H, O / OT, B), dim3(256), 0, stream>>>(x, weight, bias, att, out);
    }
}